// Round 1
// baseline (460.373 us; speedup 1.0000x reference)
//
#include <hip/hip_runtime.h>
#include <cstdint>
#include <cstddef>

#define B_   4
#define S_   1024
#define D_   1024
#define H_   16
#define DH_  64
#define F_   4096
#define MTOT 4096   // B_*S_

typedef __bf16 bf16x8 __attribute__((ext_vector_type(8)));
typedef float  f32x4  __attribute__((ext_vector_type(4)));
typedef unsigned short u16x8 __attribute__((ext_vector_type(8)));

__device__ __forceinline__ unsigned short f2bf(float f){
  uint32_t u = __builtin_bit_cast(uint32_t, f);
  u += 0x7fffu + ((u >> 16) & 1u);          // round-to-nearest-even
  return (unsigned short)(u >> 16);
}

__device__ __forceinline__ void gload_lds16(const void* g, void* l){
  __builtin_amdgcn_global_load_lds((__attribute__((address_space(1))) void*)(g),
                                   (__attribute__((address_space(3))) void*)(l),
                                   16, 0, 0);
}

// ---------------- weight transpose + fp32->bf16 convert: W[K][N] -> WT[N][K] ----------------
__global__ __launch_bounds__(256) void transpose_bf16(const float* __restrict__ W,
                                                      unsigned short* __restrict__ WT,
                                                      int K, int N){
  __shared__ float tile[32][33];
  const int tx = threadIdx.x, ty = threadIdx.y;      // 32 x 8
  const int n0 = blockIdx.x * 32, k0 = blockIdx.y * 32;
  #pragma unroll
  for (int i = 0; i < 4; ++i)
    tile[ty + i*8][tx] = W[(size_t)(k0 + ty + i*8) * N + n0 + tx];
  __syncthreads();
  #pragma unroll
  for (int i = 0; i < 4; ++i)
    WT[(size_t)(n0 + ty + i*8) * K + k0 + tx] = f2bf(tile[tx][ty + i*8]);
}

// ---------------- LayerNorm (rows of 1024) fp32 in -> bf16 out ----------------
__global__ __launch_bounds__(256) void ln_kernel(const float* __restrict__ x,
                                                 const float* __restrict__ g,
                                                 const float* __restrict__ b,
                                                 unsigned short* __restrict__ out){
  const int row = blockIdx.x;
  const int tid = threadIdx.x;
  float4 xv = ((const float4*)(x + (size_t)row * D_))[tid];
  float s  = xv.x + xv.y + xv.z + xv.w;
  float s2 = xv.x*xv.x + xv.y*xv.y + xv.z*xv.z + xv.w*xv.w;
  #pragma unroll
  for (int off = 32; off > 0; off >>= 1){
    s  += __shfl_down(s, off);
    s2 += __shfl_down(s2, off);
  }
  __shared__ float ws1[4], ws2[4];
  const int w = tid >> 6, lane = tid & 63;
  if (lane == 0){ ws1[w] = s; ws2[w] = s2; }
  __syncthreads();
  const float tot  = ws1[0] + ws1[1] + ws1[2] + ws1[3];
  const float tot2 = ws2[0] + ws2[1] + ws2[2] + ws2[3];
  const float mean = tot * (1.0f / D_);
  const float var  = tot2 * (1.0f / D_) - mean * mean;
  const float rstd = rsqrtf(var + 1e-3f);
  const int c0 = tid * 4;
  ushort4 o;
  o.x = f2bf((xv.x - mean) * rstd * g[c0+0] + b[c0+0]);
  o.y = f2bf((xv.y - mean) * rstd * g[c0+1] + b[c0+1]);
  o.z = f2bf((xv.z - mean) * rstd * g[c0+2] + b[c0+2]);
  o.w = f2bf((xv.w - mean) * rstd * g[c0+3] + b[c0+3]);
  *(ushort4*)(out + (size_t)row * D_ + c0) = o;
}

// ---------------- bf16 GEMM: C[M][N] = A[M][K] @ B (BT[N][K]) + epilogue ----------------
// EPI 0: out_bf16 = acc + bias                          (QKV)
// EPI 1: out_f32  = acc + bias + resid                  (attn out-proj + residual)
// EPI 2: out_bf16 = gelu_exact(acc + bias)              (FFN1)
// EPI 3: out_f32  = (acc + bias + resid) * (1-pad[row]) (FFN2 + residual + pad mask)
template<int EPI>
__global__ __launch_bounds__(256) void gemm_bt(const unsigned short* __restrict__ A,
                                               const unsigned short* __restrict__ BT,
                                               const float* __restrict__ bias,
                                               const float* __restrict__ resid,
                                               const float* __restrict__ pad,
                                               unsigned short* __restrict__ outB,
                                               float* __restrict__ outF,
                                               int N, int K){
  __shared__ unsigned short As[128 * 32];
  __shared__ unsigned short Bs[128 * 32];
  const int tid  = threadIdx.x;
  const int lane = tid & 63, w = tid >> 6;
  const int wr = w >> 1, wc = w & 1;
  const int lm = lane & 15, l4 = lane >> 4;
  const int m0 = blockIdx.x * 128, n0 = blockIdx.y * 128;

  // staging map: elem = chunk*2048 + tid*8 ; row = elem/32 ; col = elem%32
  const int e0 = tid * 8;
  const int r0 = e0 >> 5, c0 = e0 & 31;
  const unsigned short* Ag0 = A  + (size_t)(m0 + r0)      * K + c0;
  const unsigned short* Ag1 = A  + (size_t)(m0 + r0 + 64) * K + c0;
  const unsigned short* Bg0 = BT + (size_t)(n0 + r0)      * K + c0;
  const unsigned short* Bg1 = BT + (size_t)(n0 + r0 + 64) * K + c0;

  f32x4 acc[4][4] = {};
  for (int k0 = 0; k0 < K; k0 += 32){
    gload_lds16(Ag0 + k0, &As[0    + w*512]);
    gload_lds16(Ag1 + k0, &As[2048 + w*512]);
    gload_lds16(Bg0 + k0, &Bs[0    + w*512]);
    gload_lds16(Bg1 + k0, &Bs[2048 + w*512]);
    __syncthreads();
    bf16x8 a[4], bb[4];
    #pragma unroll
    for (int m = 0; m < 4; ++m)
      a[m] = *(const bf16x8*)&As[(wr*64 + m*16 + lm)*32 + l4*8];
    #pragma unroll
    for (int n = 0; n < 4; ++n)
      bb[n] = *(const bf16x8*)&Bs[(wc*64 + n*16 + lm)*32 + l4*8];
    #pragma unroll
    for (int m = 0; m < 4; ++m)
      #pragma unroll
      for (int n = 0; n < 4; ++n)
        acc[m][n] = __builtin_amdgcn_mfma_f32_16x16x32_bf16(a[m], bb[n], acc[m][n], 0, 0, 0);
    __syncthreads();
  }

  #pragma unroll
  for (int m = 0; m < 4; ++m){
    #pragma unroll
    for (int n = 0; n < 4; ++n){
      #pragma unroll
      for (int r = 0; r < 4; ++r){
        const int row = m0 + wr*64 + m*16 + l4*4 + r;
        const int col = n0 + wc*64 + n*16 + lm;
        const size_t idx = (size_t)row * N + col;
        float vv = acc[m][n][r] + bias[col];
        if constexpr (EPI == 0){
          outB[idx] = f2bf(vv);
        } else if constexpr (EPI == 1){
          outF[idx] = vv + resid[idx];
        } else if constexpr (EPI == 2){
          outB[idx] = f2bf(0.5f * vv * (1.0f + erff(vv * 0.70710678118654752f)));
        } else {
          float t = vv + resid[idx];
          outF[idx] = t * (1.0f - pad[row]);
        }
      }
    }
  }
}

// ---------------- flash attention: q,k,v bf16 [B,S,D]; bias f32 [B,H,S,S]; -> ctx bf16 ----------------
__global__ __launch_bounds__(256) void attn_kernel(const unsigned short* __restrict__ q,
                                                   const unsigned short* __restrict__ k,
                                                   const unsigned short* __restrict__ v,
                                                   const float* __restrict__ abias,
                                                   const float* __restrict__ amask,
                                                   const float* __restrict__ pad,
                                                   unsigned short* __restrict__ ctx){
  const int tt = blockIdx.x, h = blockIdx.y, b = blockIdx.z;
  const int t0 = tt * 64;
  const int tid = threadIdx.x;
  const int lane = tid & 63, w = tid >> 6;
  const int lm = lane & 15, l4 = lane >> 4;

  __shared__ unsigned short Ks[64 * 64];     // [s][dh]
  __shared__ unsigned short VTs[64 * 64];    // [dh][s]
  __shared__ unsigned short Ps[4][16 * 64];  // per-wave P tile [t][s]

  // Q fragments (A operand): row=lm, k = kc*32 + l4*8 + j
  bf16x8 aq[2];
  {
    const int tg = t0 + w*16 + lm;
    const size_t qb = (size_t)(b*S_ + tg) * D_ + h*DH_;
    aq[0] = *(const bf16x8*)&q[qb + 0  + l4*8];
    aq[1] = *(const bf16x8*)&q[qb + 32 + l4*8];
  }

  float keep_t[4];
  #pragma unroll
  for (int r = 0; r < 4; ++r)
    keep_t[r] = 1.0f - pad[b*S_ + t0 + w*16 + l4*4 + r];

  f32x4 accO[4] = {};
  float mrow[4] = {-1e30f, -1e30f, -1e30f, -1e30f};
  float lrow[4] = {};

  const int e = tid * 8;
  const int sr = e >> 6, dc = e & 63;   // K staging map

  for (int s0 = 0; s0 < S_; s0 += 64){
    gload_lds16(&k[(size_t)(b*S_ + s0 + sr)      * D_ + h*DH_ + dc], &Ks[0    + w*512]);
    gload_lds16(&k[(size_t)(b*S_ + s0 + 32 + sr) * D_ + h*DH_ + dc], &Ks[2048 + w*512]);
    #pragma unroll
    for (int c = 0; c < 2; ++c){
      const int sv = c*32 + (tid >> 3);
      const int dv = (tid & 7) * 8;
      u16x8 vv = *(const u16x8*)&v[(size_t)(b*S_ + s0 + sv) * D_ + h*DH_ + dv];
      #pragma unroll
      for (int j = 0; j < 8; ++j) VTs[(dv + j)*64 + sv] = (unsigned short)vv[j];
    }
    __syncthreads();

    // S = Q K^T
    f32x4 accS[4] = {};
    #pragma unroll
    for (int n = 0; n < 4; ++n){
      #pragma unroll
      for (int kc = 0; kc < 2; ++kc){
        bf16x8 bk_ = *(const bf16x8*)&Ks[(n*16 + lm)*64 + kc*32 + l4*8];
        accS[n] = __builtin_amdgcn_mfma_f32_16x16x32_bf16(aq[kc], bk_, accS[n], 0, 0, 0);
      }
    }

    // logits = S/8 + bias - 1e9*(1-mask)
    float lg[4][4];
    #pragma unroll
    for (int n = 0; n < 4; ++n){
      const int sg = s0 + n*16 + lm;
      const float keep_s = 1.0f - pad[b*S_ + sg];
      #pragma unroll
      for (int r = 0; r < 4; ++r){
        const int tg = t0 + w*16 + l4*4 + r;
        const float bb = abias[((size_t)((b*H_ + h)*S_) + tg) * S_ + sg];
        const float mm = amask[(size_t)(b*S_ + tg) * S_ + sg] * keep_t[r] * keep_s;
        lg[n][r] = accS[n][r] * 0.125f + bb - 1e9f * (1.0f - mm);
      }
    }

    // online softmax (rows owned by 16-lane groups)
    float ef[4];
    #pragma unroll
    for (int r = 0; r < 4; ++r){
      float mx = fmaxf(fmaxf(lg[0][r], lg[1][r]), fmaxf(lg[2][r], lg[3][r]));
      mx = fmaxf(mx, __shfl_xor(mx, 1));
      mx = fmaxf(mx, __shfl_xor(mx, 2));
      mx = fmaxf(mx, __shfl_xor(mx, 4));
      mx = fmaxf(mx, __shfl_xor(mx, 8));
      const float mnew = fmaxf(mrow[r], mx);
      ef[r] = __expf(mrow[r] - mnew);
      mrow[r] = mnew;
    }
    float ps[4] = {};
    #pragma unroll
    for (int n = 0; n < 4; ++n){
      #pragma unroll
      for (int r = 0; r < 4; ++r){
        const float pv = __expf(lg[n][r] - mrow[r]);
        lg[n][r] = pv;
        ps[r] += pv;
      }
    }
    #pragma unroll
    for (int r = 0; r < 4; ++r){
      float s = ps[r];
      s += __shfl_xor(s, 1); s += __shfl_xor(s, 2);
      s += __shfl_xor(s, 4); s += __shfl_xor(s, 8);
      lrow[r] = lrow[r] * ef[r] + s;
    }
    #pragma unroll
    for (int n = 0; n < 4; ++n)
      #pragma unroll
      for (int r = 0; r < 4; ++r) accO[n][r] *= ef[r];

    // P -> LDS (re-layout for A operand of PV)
    #pragma unroll
    for (int n = 0; n < 4; ++n)
      #pragma unroll
      for (int r = 0; r < 4; ++r)
        Ps[w][(l4*4 + r)*64 + n*16 + lm] = f2bf(lg[n][r]);
    __syncthreads();

    // O += P V
    #pragma unroll
    for (int ks = 0; ks < 2; ++ks){
      bf16x8 ap = *(const bf16x8*)&Ps[w][lm*64 + ks*32 + l4*8];
      #pragma unroll
      for (int n = 0; n < 4; ++n){
        bf16x8 bv_ = *(const bf16x8*)&VTs[(n*16 + lm)*64 + ks*32 + l4*8];
        accO[n] = __builtin_amdgcn_mfma_f32_16x16x32_bf16(ap, bv_, accO[n], 0, 0, 0);
      }
    }
    __syncthreads();
  }

  #pragma unroll
  for (int n = 0; n < 4; ++n)
    #pragma unroll
    for (int r = 0; r < 4; ++r){
      const int tg = t0 + w*16 + l4*4 + r;
      ctx[(size_t)(b*S_ + tg) * D_ + h*DH_ + n*16 + lm] = f2bf(accO[n][r] / lrow[r]);
    }
}

// ---------------- host ----------------
extern "C" void kernel_launch(void* const* d_in, const int* in_sizes, int n_in,
                              void* d_out, int out_size, void* d_ws, size_t ws_size,
                              hipStream_t stream){
  (void)in_sizes; (void)n_in; (void)out_size; (void)ws_size;
  const float* x     = (const float*)d_in[0];
  const float* pad   = (const float*)d_in[1];
  const float* abias = (const float*)d_in[2];
  const float* amask = (const float*)d_in[3];
  const float* ln1g  = (const float*)d_in[4];
  const float* ln1b  = (const float*)d_in[5];
  const float* wq    = (const float*)d_in[6];
  const float* bq    = (const float*)d_in[7];
  const float* wk    = (const float*)d_in[8];
  const float* bk    = (const float*)d_in[9];
  const float* wv    = (const float*)d_in[10];
  const float* bv    = (const float*)d_in[11];
  const float* wo    = (const float*)d_in[12];
  const float* bo    = (const float*)d_in[13];
  const float* ln2g  = (const float*)d_in[14];
  const float* ln2b  = (const float*)d_in[15];
  const float* w1    = (const float*)d_in[16];
  const float* b1    = (const float*)d_in[17];
  const float* w2    = (const float*)d_in[18];
  const float* b2    = (const float*)d_in[19];
  float* out = (float*)d_out;

  char* p = (char*)d_ws;
  auto take = [&](size_t bytes){ void* r = (void*)p; p += bytes; return r; };
  unsigned short* xn   = (unsigned short*)take((size_t)MTOT * D_ * 2);
  unsigned short* qb   = (unsigned short*)take((size_t)MTOT * D_ * 2);
  unsigned short* kb   = (unsigned short*)take((size_t)MTOT * D_ * 2);
  unsigned short* vb   = (unsigned short*)take((size_t)MTOT * D_ * 2);
  unsigned short* ctx  = (unsigned short*)take((size_t)MTOT * D_ * 2);
  unsigned short* yn   = (unsigned short*)take((size_t)MTOT * D_ * 2);
  unsigned short* hb   = (unsigned short*)take((size_t)MTOT * F_ * 2);
  float*          ao   = (float*)take((size_t)MTOT * D_ * 4);
  unsigned short* wqT  = (unsigned short*)take((size_t)D_ * D_ * 2);
  unsigned short* wkT  = (unsigned short*)take((size_t)D_ * D_ * 2);
  unsigned short* wvT  = (unsigned short*)take((size_t)D_ * D_ * 2);
  unsigned short* woT  = (unsigned short*)take((size_t)D_ * D_ * 2);
  unsigned short* w1T  = (unsigned short*)take((size_t)D_ * F_ * 2);
  unsigned short* w2T  = (unsigned short*)take((size_t)D_ * F_ * 2);

  const dim3 tb(32, 8);
  transpose_bf16<<<dim3(D_/32, D_/32), tb, 0, stream>>>(wq, wqT, D_, D_);
  transpose_bf16<<<dim3(D_/32, D_/32), tb, 0, stream>>>(wk, wkT, D_, D_);
  transpose_bf16<<<dim3(D_/32, D_/32), tb, 0, stream>>>(wv, wvT, D_, D_);
  transpose_bf16<<<dim3(D_/32, D_/32), tb, 0, stream>>>(wo, woT, D_, D_);
  transpose_bf16<<<dim3(F_/32, D_/32), tb, 0, stream>>>(w1, w1T, D_, F_);
  transpose_bf16<<<dim3(D_/32, F_/32), tb, 0, stream>>>(w2, w2T, F_, D_);

  ln_kernel<<<MTOT, 256, 0, stream>>>(x, ln1g, ln1b, xn);

  gemm_bt<0><<<dim3(MTOT/128, D_/128), 256, 0, stream>>>(xn, wqT, bq, nullptr, nullptr, qb, nullptr, D_, D_);
  gemm_bt<0><<<dim3(MTOT/128, D_/128), 256, 0, stream>>>(xn, wkT, bk, nullptr, nullptr, kb, nullptr, D_, D_);
  gemm_bt<0><<<dim3(MTOT/128, D_/128), 256, 0, stream>>>(xn, wvT, bv, nullptr, nullptr, vb, nullptr, D_, D_);

  attn_kernel<<<dim3(S_/64, H_, B_), 256, 0, stream>>>(qb, kb, vb, abias, amask, pad, ctx);

  gemm_bt<1><<<dim3(MTOT/128, D_/128), 256, 0, stream>>>(ctx, woT, bo, x, nullptr, nullptr, ao, D_, D_);

  ln_kernel<<<MTOT, 256, 0, stream>>>(ao, ln2g, ln2b, yn);

  gemm_bt<2><<<dim3(MTOT/128, F_/128), 256, 0, stream>>>(yn, w1T, b1, nullptr, nullptr, hb, nullptr, F_, D_);

  gemm_bt<3><<<dim3(MTOT/128, D_/128), 256, 0, stream>>>(hb, w2T, b2, ao, pad, nullptr, out, D_, F_);
}